// Round 6
// baseline (209.969 us; speedup 1.0000x reference)
//
#include <hip/hip_runtime.h>

// Problem constants
#define B_   4
#define C_   64
#define H_   192
#define W_   640
#define D_   96     // disparities
#define TWB  64     // w1 columns per tile
#define NDL  7      // 16-wide delta tiles covering d in [0,96)
#define HW_  (H_ * W_)
#define GP   68     // Gs pitch (floats), mult of 4, non-pow2
#define T_   6      // tiles per block
#define NBLK 1280   // blocks; NBLK * T_ = 7680 tiles

typedef __attribute__((ext_vector_type(8))) short short8;
typedef __attribute__((ext_vector_type(4))) float float4v;

// bank swizzle: injects k bits 0..5 into the 8x16B slot index of a 128B row
#define SWZ(x) ((((x) ^ ((x) >> 3)) & 7) << 3)

// packed f32x2 -> bf16x2 (single HW instruction, RTNE)
__device__ inline unsigned int pk2(float lo, float hi) {
    unsigned int r;
    asm("v_cvt_pk_bf16_f32 %0, %1, %2" : "=v"(r) : "v"(lo), "v"(hi));
    return r;
}

// out[b,0,d,h,w] = sum_c L[b,c,h,w] * R[b,c,h,(w - d*S) mod W] = G[w][w - S*d]
template <int S>
__global__ __launch_bounds__(256, 4)
void cost_volume_mfma(const float* __restrict__ Lp,
                      const float* __restrict__ Rp,
                      const int* __restrict__ dirp,
                      float* __restrict__ out)
{
    if (dirp[0] != S) return;   // self-select direction instantiation

    // 28672 B union:
    //   staging: Lb [64][64] u16 @ byte 0, Rb [160][64] u16 @ byte 8192
    //   then reused as Gs [96][GP] f32 (26112 B)
    __shared__ unsigned int smem[7168];
    unsigned int* Lw = smem;
    unsigned int* Rw = smem + 2048;                 // byte 8192
    const unsigned short* Lb = (const unsigned short*)smem;         // byte 0
    const unsigned short* Rb = (const unsigned short*)smem + 4096;  // byte 8192
    float* Gs = (float*)smem;

    const int tid  = threadIdx.x;
    const int lane = tid & 63;
    const int wv   = tid >> 6;
    const int n15  = lane & 15;
    const int lg   = lane >> 4;

    // staging / epilogue thread constants (tile-independent)
    const int w4 = tid & 15;          // L-stage + epilogue w group
    const int cL = (tid >> 4) * 2;    // L channel pair (0..30)
    const int k8 = tid & 7;           // R k4 low bits
    const int cR = (tid >> 3) * 2;    // R channel pair (0..62)

    // XCD-chunked bijective tile assignment: block kb -> 6 consecutive nids
    const int kb = blockIdx.x;
    const int nb = ((kb & 7) * (NBLK / 8) + (kb >> 3)) * T_;

    float4 pf[14];   // register prefetch buffer: 4x L, 10x R

    auto issue = [&](int nid) {
        const int bh   = nid / 10;
        const int slab = nid - bh * 10;
        const int b  = bh / H_;
        const int h  = bh - b * H_;
        const int w0 = slab * TWB;
        const float* Lrow = Lp + ((size_t)b * C_ * H_ + h) * W_;
        const float* Rrow = Rp + ((size_t)b * C_ * H_ + h) * W_;
        const float* p0 = Lrow + (size_t)cL * HW_ + w0 + 4 * w4;
        pf[0] = *(const float4*)(p0);
        pf[1] = *(const float4*)(p0 + HW_);
        pf[2] = *(const float4*)(p0 + (size_t)32 * HW_);
        pf[3] = *(const float4*)(p0 + (size_t)33 * HW_);
        const int rbase = (S == 1) ? (w0 - 96) : w0;
        const float* pc = Rrow + (size_t)cR * HW_;
#pragma unroll
        for (int u0 = 0; u0 < 5; ++u0) {
            int col = rbase + 4 * (k8 + 8 * u0);   // float4 never straddles wrap
            if (col < 0)    col += W_;
            if (col >= W_)  col -= W_;
            pf[4 + 2 * u0] = *(const float4*)(pc + col);
            pf[5 + 2 * u0] = *(const float4*)(pc + HW_ + col);
        }
    };

    issue(nb);   // prologue: tile 0 loads in flight

    for (int t = 0; t < T_; ++t) {
        const int nid  = nb + t;
        const int bh   = nid / 10;
        const int slab = nid - bh * 10;
        const int b  = bh / H_;
        const int h  = bh - b * H_;
        const int w0 = slab * TWB;

        // ---- convert pf -> LDS staging (consumes pf) ----
#pragma unroll
        for (int u0 = 0; u0 < 2; ++u0) {
            const int c = cL + 32 * u0;
            const float4 a = pf[2 * u0], q = pf[2 * u0 + 1];
            const float av[4] = {a.x, a.y, a.z, a.w};
            const float qv[4] = {q.x, q.y, q.z, q.w};
#pragma unroll
            for (int j = 0; j < 4; ++j) {
                const int w = 4 * w4 + j;
                Lw[w * 32 + ((c ^ SWZ(w)) >> 1)] = pk2(av[j], qv[j]);
            }
        }
#pragma unroll
        for (int u0 = 0; u0 < 5; ++u0) {
            const float4 a = pf[4 + 2 * u0], q = pf[5 + 2 * u0];
            const float av[4] = {a.x, a.y, a.z, a.w};
            const float qv[4] = {q.x, q.y, q.z, q.w};
#pragma unroll
            for (int j = 0; j < 4; ++j) {
                const int k = 4 * (k8 + 8 * u0) + j;
                Rw[k * 32 + ((cR ^ SWZ(k)) >> 1)] = pk2(av[j], qv[j]);
            }
        }

        if (t + 1 < T_) issue(nid + 1);   // prefetch next tile (flies across barriers)

        __syncthreads();   // staging visible

        // ---- MFMA: wave wv owns w1 tile [w0+16wv, +16) ----
        short8 afrag[2];
        {
            const int w = 16 * wv + n15;
#pragma unroll
            for (int q = 0; q < 2; ++q) {
                const int c = lg * 8 + 32 * q;
                afrag[q] = *(const short8*)&Lb[w * 64 + (c ^ SWZ(w))];
            }
        }

        float4v acc[NDL];
#pragma unroll
        for (int dl = 0; dl < NDL; ++dl) acc[dl] = (float4v)0.f;

#pragma unroll
        for (int dl = 0; dl < NDL; ++dl) {
            const int rlo = (S == 1) ? (96 + 16 * (wv - dl)) : (16 * (wv + dl));
            const int k   = rlo + n15;
#pragma unroll
            for (int q = 0; q < 2; ++q) {
                const int c = lg * 8 + 32 * q;
                const short8 bfrag = *(const short8*)&Rb[k * 64 + (c ^ SWZ(k))];
                acc[dl] = __builtin_amdgcn_mfma_f32_16x16x32_bf16(afrag[q], bfrag, acc[dl], 0, 0, 0);
            }
        }
        __syncthreads();   // staging reads done; safe to overwrite with Gs

        // ---- scatter into Gs[d][w_local] (pitch 68) ----
        // D layout (16x16x32): n = lane&15 (w2), m = (lane>>4)*4 + reg (w1)
#pragma unroll
        for (int dl = 0; dl < NDL; ++dl) {
#pragma unroll
            for (int r = 0; r < 4; ++r) {
                const int m = lg * 4 + r;
                const int d = (S == 1) ? (16 * dl + m - n15) : (16 * dl + n15 - m);
                if (0 <= d && d < D_)
                    Gs[d * GP + 16 * wv + m] = acc[dl][r];
            }
        }
        __syncthreads();   // Gs complete

        // ---- coalesced epilogue: float4 LDS reads, float4 global stores ----
        const int dg = tid >> 4;
#pragma unroll
        for (int p = 0; p < 6; ++p) {
            const int d = dg + 16 * p;
            const float4 v = *(const float4*)&Gs[d * GP + 4 * w4];
            *(float4*)(out + ((size_t)(b * D_ + d) * H_ + h) * W_ + w0 + 4 * w4) = v;
        }

        if (t + 1 < T_) __syncthreads();   // Gs reads done before next staging write
    }
}

extern "C" void kernel_launch(void* const* d_in, const int* in_sizes, int n_in,
                              void* d_out, int out_size, void* d_ws, size_t ws_size,
                              hipStream_t stream)
{
    const float* un_l = (const float*)d_in[0];
    const float* un_r = (const float*)d_in[1];
    const int*   dirp = (const int*)d_in[2];
    float* out = (float*)d_out;

    dim3 grid(NBLK);
    dim3 block(256);

    // direction only known on device: launch both, mismatching one exits
    cost_volume_mfma<1><<<grid, block, 0, stream>>>(un_l, un_r, dirp, out);
    cost_volume_mfma<-1><<<grid, block, 0, stream>>>(un_l, un_r, dirp, out);
}

// Round 7
// 99.947 us; speedup vs baseline: 2.1008x; 2.1008x over previous
//
#include <hip/hip_runtime.h>

// Problem constants
#define B_    4
#define C_    64
#define H_    192
#define W_    640
#define D_    96     // disparities
#define TWB   128    // w1 columns per block
#define RWID  224    // staged R columns (TWB + 96)
#define NSLAB 5      // W / TWB
#define NDL   7      // 16-wide delta tiles covering d in [0,96)
#define HW_   (H_ * W_)
#define GP    132    // Gs pitch (floats), mult of 4, non-pow2
#define NWG   (NSLAB * B_ * H_)   // 3840 = 8 * 480

typedef __attribute__((ext_vector_type(8))) short short8;
typedef __attribute__((ext_vector_type(4))) float float4v;

// bank swizzle: spreads row bits into the 8x16B slot index of a 128B row
#define SWZ(x) ((((x) ^ ((x) >> 3)) & 7) << 3)

// packed f32x2 -> bf16x2 (single HW instruction, RTNE)
__device__ inline unsigned int pk2(float lo, float hi) {
    unsigned int r;
    asm("v_cvt_pk_bf16_f32 %0, %1, %2" : "=v"(r) : "v"(lo), "v"(hi));
    return r;
}

// out[b,0,d,h,w] = sum_c L[b,c,h,w] * R[b,c,h,(w - d*S) mod W] = G[w][w - S*d]
template <int S>
__global__ __launch_bounds__(512)
void cost_volume_mfma(const float* __restrict__ Lp,
                      const float* __restrict__ Rp,
                      const int* __restrict__ dirp,
                      float* __restrict__ out)
{
    if (dirp[0] != S) return;   // self-select direction instantiation

    // 50688 B union:
    //   staging: Lb [128][64] u16 @ byte 0 (16 KB), Rb [224][64] u16 @ byte 16384 (28 KB)
    //   then reused as Gs [96][GP] f32 (50688 B)
    __shared__ unsigned int smem[12672];
    unsigned int* Lw = smem;                        // u32 view of Lb
    unsigned int* Rw = smem + 4096;                 // u32 view of Rb (byte 16384)
    const unsigned short* Lb = (const unsigned short*)smem;         // byte 0
    const unsigned short* Rb = (const unsigned short*)smem + 8192;  // byte 16384
    float* Gs = (float*)smem;

    // XCD-chunked bijective swizzle: NWG = 3840 = 8 * 480
    const int orig = blockIdx.x;
    const int nid  = (orig & 7) * (NWG / 8) + (orig >> 3);
    const int bh   = nid / NSLAB;
    const int slab = nid - bh * NSLAB;
    const int b  = bh / H_;
    const int h  = bh - b * H_;
    const int w0 = slab * TWB;
    const int rbase = (S == 1) ? (w0 - 96) : w0;   // global col of Rb k=0

    const int tid = threadIdx.x;
    const float* Lrow = Lp + ((size_t)b * C_ * H_ + h) * W_;
    const float* Rrow = Rp + ((size_t)b * C_ * H_ + h) * W_;

    // ---- stage L: [128 w][64 c], units (16 cpair x 32 w4) x 2 passes ----
    {
        const int w4 = tid & 31;
        const int cp = tid >> 5;     // 0..15
#pragma unroll
        for (int p = 0; p < 2; ++p) {
            const int c = 2 * cp + 32 * p;
            const float* p0 = Lrow + (size_t)c * HW_ + w0 + 4 * w4;
            const float4 a = *(const float4*)p0;
            const float4 q = *(const float4*)(p0 + HW_);
            const float av[4] = {a.x, a.y, a.z, a.w};
            const float qv[4] = {q.x, q.y, q.z, q.w};
#pragma unroll
            for (int j = 0; j < 4; ++j) {
                const int w = 4 * w4 + j;
                Lw[w * 32 + ((c ^ SWZ(w)) >> 1)] = pk2(av[j], qv[j]);
            }
        }
    }

    // ---- stage R: [224 k][64 c], units (32 cpair x 56 k4), 4 ragged passes ----
#pragma unroll
    for (int p = 0; p < 4; ++p) {
        const int idx = tid + 512 * p;
        if (idx < 32 * 56) {
            const int cp = idx / 56;
            const int k4 = idx - cp * 56;
            const int c  = 2 * cp;
            int col = rbase + 4 * k4;    // float4 never straddles wrap
            if (col < 0)   col += W_;
            if (col >= W_) col -= W_;
            const float* pc = Rrow + (size_t)c * HW_ + col;
            const float4 a = *(const float4*)pc;
            const float4 q = *(const float4*)(pc + HW_);
            const float av[4] = {a.x, a.y, a.z, a.w};
            const float qv[4] = {q.x, q.y, q.z, q.w};
#pragma unroll
            for (int j = 0; j < 4; ++j) {
                const int k = 4 * k4 + j;
                Rw[k * 32 + ((c ^ SWZ(k)) >> 1)] = pk2(av[j], qv[j]);
            }
        }
    }
    __syncthreads();

    // ---- MFMA: wave wv (0..7) owns w1 tile [w0+16wv, +16), 7 delta tiles x K=64 ----
    const int lane = tid & 63;
    const int wv   = tid >> 6;
    const int n15  = lane & 15;
    const int lg   = lane >> 4;

    short8 afrag[2];
    {
        const int w = 16 * wv + n15;
#pragma unroll
        for (int q = 0; q < 2; ++q) {
            const int c = lg * 8 + 32 * q;
            afrag[q] = *(const short8*)&Lb[w * 64 + (c ^ SWZ(w))];
        }
    }

    float4v acc[NDL];
#pragma unroll
    for (int dl = 0; dl < NDL; ++dl) acc[dl] = (float4v)0.f;

#pragma unroll
    for (int dl = 0; dl < NDL; ++dl) {
        const int rlo = (S == 1) ? (96 + 16 * (wv - dl)) : (16 * (wv + dl));
        const int k   = rlo + n15;          // 0..223
#pragma unroll
        for (int q = 0; q < 2; ++q) {
            const int c = lg * 8 + 32 * q;
            const short8 bfrag = *(const short8*)&Rb[k * 64 + (c ^ SWZ(k))];
            acc[dl] = __builtin_amdgcn_mfma_f32_16x16x32_bf16(afrag[q], bfrag, acc[dl], 0, 0, 0);
        }
    }
    __syncthreads();   // staging reads done; safe to overwrite with Gs

    // ---- scatter into Gs[d][w_local] (pitch 132) ----
    // D layout (16x16x32): n = lane&15 (w2), m = (lane>>4)*4 + reg (w1)
#pragma unroll
    for (int dl = 0; dl < NDL; ++dl) {
#pragma unroll
        for (int r = 0; r < 4; ++r) {
            const int m = lg * 4 + r;
            const int d = (S == 1) ? (16 * dl + m - n15) : (16 * dl + n15 - m);
            if (0 <= d && d < D_)
                Gs[d * GP + 16 * wv + m] = acc[dl][r];
        }
    }
    __syncthreads();   // Gs complete

    // ---- coalesced epilogue: float4 LDS reads, float4 global stores ----
    const int w4 = tid & 31;     // 32 float4 = 128 cols
    const int dg = tid >> 5;     // 16 d groups
#pragma unroll
    for (int p = 0; p < 6; ++p) {
        const int d = dg + 16 * p;
        const float4 v = *(const float4*)&Gs[d * GP + 4 * w4];
        *(float4*)(out + ((size_t)(b * D_ + d) * H_ + h) * W_ + w0 + 4 * w4) = v;
    }
}

extern "C" void kernel_launch(void* const* d_in, const int* in_sizes, int n_in,
                              void* d_out, int out_size, void* d_ws, size_t ws_size,
                              hipStream_t stream)
{
    const float* un_l = (const float*)d_in[0];
    const float* un_r = (const float*)d_in[1];
    const int*   dirp = (const int*)d_in[2];
    float* out = (float*)d_out;

    dim3 grid(NWG);    // 3840
    dim3 block(512);

    // direction only known on device: launch both, mismatching one exits
    cost_volume_mfma<1><<<grid, block, 0, stream>>>(un_l, un_r, dirp, out);
    cost_volume_mfma<-1><<<grid, block, 0, stream>>>(un_l, un_r, dirp, out);
}

// Round 8
// 95.625 us; speedup vs baseline: 2.1957x; 1.0452x over previous
//
#include <hip/hip_runtime.h>

// Problem constants
#define B_   4
#define C_   64
#define H_   192
#define W_   640
#define D_   96     // disparities
#define TWB  64     // w1 columns per block
#define NDL  7      // 16-wide delta tiles covering d in [0,96)
#define HW_  (H_ * W_)
#define GP   97     // Gs pitch: [w_local][d], odd -> bank = (w+d)%32, <=2-way
#define NWG  7680   // (W/TWB) * B * H = 8 * 960

typedef __attribute__((ext_vector_type(8))) short short8;
typedef __attribute__((ext_vector_type(4))) float float4v;

// bank swizzle: spreads row bits into the 8x16B slot index of a 128B row
#define SWZ(x) ((((x) ^ ((x) >> 3)) & 7) << 3)

// packed f32x2 -> bf16x2 (single HW instruction, RTNE)
__device__ inline unsigned int pk2(float lo, float hi) {
    unsigned int r;
    asm("v_cvt_pk_bf16_f32 %0, %1, %2" : "=v"(r) : "v"(lo), "v"(hi));
    return r;
}

// out[b,0,d,h,w] = sum_c L[b,c,h,w] * R[b,c,h,(w - d*s) mod W] = G[w][w - s*d]
__global__ __launch_bounds__(256)
void cost_volume_mfma(const float* __restrict__ Lp,
                      const float* __restrict__ Rp,
                      const int* __restrict__ dirp,
                      float* __restrict__ out)
{
    const int s = dirp[0];   // +1 or -1, uniform across grid

    // 28672 B union:
    //   staging: Lb [64][64] u16 @ byte 0, Rb [160][64] u16 @ byte 8192
    //   then reused as Gs [64 w][GP=97 d] f32 (24832 B)
    __shared__ unsigned int smem[7168];
    unsigned int* Lw = smem;
    unsigned int* Rw = smem + 2048;                 // byte 8192
    const unsigned short* Lb = (const unsigned short*)smem;         // byte 0
    const unsigned short* Rb = (const unsigned short*)smem + 4096;  // byte 8192
    float* Gs = (float*)smem;

    // XCD-chunked bijective swizzle: NWG = 7680 = 8 * 960
    const int orig = blockIdx.x;
    const int nid  = (orig & 7) * (NWG / 8) + (orig >> 3);
    const int bh   = nid / 10;
    const int slab = nid - bh * 10;
    const int b  = bh / H_;
    const int h  = bh - b * H_;
    const int w0 = slab * TWB;
    const int rbase = (s == 1) ? (w0 - 96) : w0;    // global col of Rb k=0
    const int rbias = (s == 1) ? 96 : 0;            // B-frag tile bias

    const int tid = threadIdx.x;
    const float* Lrow = Lp + ((size_t)b * C_ * H_ + h) * W_;
    const float* Rrow = Rp + ((size_t)b * C_ * H_ + h) * W_;

    const int w4 = tid & 15;          // L-stage + epilogue w group
    const int cL = (tid >> 4) * 2;    // L channel pair (0..30)
    const int k8 = tid & 7;           // R k4 low bits
    const int cR = (tid >> 3) * 2;    // R channel pair (0..62)

    // ---- issue ALL 14 stage loads first (MLP), statically-indexed regs ----
    float4 pf[14];
    {
        const float* p0 = Lrow + (size_t)cL * HW_ + w0 + 4 * w4;
        pf[0] = *(const float4*)(p0);
        pf[1] = *(const float4*)(p0 + HW_);
        pf[2] = *(const float4*)(p0 + (size_t)32 * HW_);
        pf[3] = *(const float4*)(p0 + (size_t)33 * HW_);
        const float* pc = Rrow + (size_t)cR * HW_;
#pragma unroll
        for (int u0 = 0; u0 < 5; ++u0) {
            int col = rbase + 4 * (k8 + 8 * u0);   // float4 never straddles wrap
            if (col < 0)   col += W_;
            if (col >= W_) col -= W_;
            pf[4 + 2 * u0] = *(const float4*)(pc + col);
            pf[5 + 2 * u0] = *(const float4*)(pc + HW_ + col);
        }
    }
    __builtin_amdgcn_sched_barrier(0);   // keep loads issued above the converts

    // ---- convert + LDS staging writes ----
#pragma unroll
    for (int u0 = 0; u0 < 2; ++u0) {
        const int c = cL + 32 * u0;
        const float4 a = pf[2 * u0], q = pf[2 * u0 + 1];
        const float av[4] = {a.x, a.y, a.z, a.w};
        const float qv[4] = {q.x, q.y, q.z, q.w};
#pragma unroll
        for (int j = 0; j < 4; ++j) {
            const int w = 4 * w4 + j;
            Lw[w * 32 + ((c ^ SWZ(w)) >> 1)] = pk2(av[j], qv[j]);
        }
    }
#pragma unroll
    for (int u0 = 0; u0 < 5; ++u0) {
        const float4 a = pf[4 + 2 * u0], q = pf[5 + 2 * u0];
        const float av[4] = {a.x, a.y, a.z, a.w};
        const float qv[4] = {q.x, q.y, q.z, q.w};
#pragma unroll
        for (int j = 0; j < 4; ++j) {
            const int k = 4 * (k8 + 8 * u0) + j;
            Rw[k * 32 + ((cR ^ SWZ(k)) >> 1)] = pk2(av[j], qv[j]);
        }
    }
    __syncthreads();   // staging visible

    // ---- MFMA: wave wv owns w1 tile [w0+16wv, +16), 7 delta tiles x K=64 ----
    const int lane = tid & 63;
    const int wv   = tid >> 6;
    const int n15  = lane & 15;
    const int lg   = lane >> 4;

    short8 afrag[2];
    {
        const int w = 16 * wv + n15;
#pragma unroll
        for (int q = 0; q < 2; ++q) {
            const int c = lg * 8 + 32 * q;
            afrag[q] = *(const short8*)&Lb[w * 64 + (c ^ SWZ(w))];
        }
    }

    float4v acc[NDL];
#pragma unroll
    for (int dl = 0; dl < NDL; ++dl) acc[dl] = (float4v)0.f;

#pragma unroll
    for (int dl = 0; dl < NDL; ++dl) {
        const int k = rbias + 16 * wv - s * 16 * dl + n15;   // 0..159
#pragma unroll
        for (int q = 0; q < 2; ++q) {
            const int c = lg * 8 + 32 * q;
            const short8 bfrag = *(const short8*)&Rb[k * 64 + (c ^ SWZ(k))];
            acc[dl] = __builtin_amdgcn_mfma_f32_16x16x32_bf16(afrag[q], bfrag, acc[dl], 0, 0, 0);
        }
    }
    __syncthreads();   // staging reads done; safe to overwrite with Gs

    // ---- scatter into Gs[w_local][d] (pitch 97, odd -> conflict-free) ----
    // D layout (16x16x32): n = lane&15 (w2), m = (lane>>4)*4 + reg (w1)
#pragma unroll
    for (int dl = 0; dl < NDL; ++dl) {
#pragma unroll
        for (int r = 0; r < 4; ++r) {
            const int m = lg * 4 + r;
            const int d = 16 * dl + s * (m - n15);
            if (0 <= d && d < D_)
                Gs[(16 * wv + m) * GP + d] = acc[dl][r];
        }
    }
    __syncthreads();   // Gs complete

    // ---- epilogue: scalar LDS reads (bank-clean), float4 global stores ----
    const int dg = tid >> 4;
#pragma unroll
    for (int p = 0; p < 6; ++p) {
        const int d = dg + 16 * p;
        float4 v;
        v.x = Gs[(4 * w4 + 0) * GP + d];
        v.y = Gs[(4 * w4 + 1) * GP + d];
        v.z = Gs[(4 * w4 + 2) * GP + d];
        v.w = Gs[(4 * w4 + 3) * GP + d];
        *(float4*)(out + ((size_t)(b * D_ + d) * H_ + h) * W_ + w0 + 4 * w4) = v;
    }
}

extern "C" void kernel_launch(void* const* d_in, const int* in_sizes, int n_in,
                              void* d_out, int out_size, void* d_ws, size_t ws_size,
                              hipStream_t stream)
{
    const float* un_l = (const float*)d_in[0];
    const float* un_r = (const float*)d_in[1];
    const int*   dirp = (const int*)d_in[2];
    float* out = (float*)d_out;

    dim3 grid(NWG);    // 7680
    dim3 block(256);

    // single kernel, runtime-uniform direction
    cost_volume_mfma<<<grid, block, 0, stream>>>(un_l, un_r, dirp, out);
}